// Round 1
// baseline (225.395 us; speedup 1.0000x reference)
//
#include <hip/hip_runtime.h>

// Network_31945966748134: per-row MLP collapse.
//   h = relu(x . w_in)                      (x: [B,4], w_in: [1,4])
//   9x: h = relu(w_hidden[i] * h)  ==  h *= prod(max(w_hidden[i],0))   (h >= 0)
//   logits = h * w_out[j], j=0..2  -> softmax(3)
// Memory-bound: 134 MB read + 101 MB write. Each thread does 4 rows so the
// 12 output floats are 3 aligned float4 stores.

__global__ __launch_bounds__(256) void Network_31945966748134_kernel(
    const float* __restrict__ x,
    const float* __restrict__ w_in,
    const float* __restrict__ w_hidden,
    const float* __restrict__ w_out,
    float* __restrict__ out,
    int nrows)
{
    // Wave-uniform weight loads (uniform address -> scalar loads, cached).
    const float wi0 = w_in[0], wi1 = w_in[1], wi2 = w_in[2], wi3 = w_in[3];
    float c = 1.0f;
#pragma unroll
    for (int i = 0; i < 9; ++i) c *= fmaxf(w_hidden[i], 0.0f);
    const float wo0 = w_out[0], wo1 = w_out[1], wo2 = w_out[2];

    const int t = blockIdx.x * blockDim.x + threadIdx.x;
    const int row0 = t * 4;
    if (row0 >= nrows) return;

    const float4* __restrict__ xv = (const float4*)x;  // one float4 per row
    float4 xs0 = xv[row0 + 0];
    float4 xs1 = xv[row0 + 1];
    float4 xs2 = xv[row0 + 2];
    float4 xs3 = xv[row0 + 3];

    float res[12];
    float4 xs[4] = {xs0, xs1, xs2, xs3};
#pragma unroll
    for (int k = 0; k < 4; ++k) {
        float h = xs[k].x * wi0 + xs[k].y * wi1 + xs[k].z * wi2 + xs[k].w * wi3;
        h = fmaxf(h, 0.0f) * c;
        const float l0 = h * wo0, l1 = h * wo1, l2 = h * wo2;
        const float m = fmaxf(fmaxf(l0, l1), l2);
        const float e0 = __expf(l0 - m);
        const float e1 = __expf(l1 - m);
        const float e2 = __expf(l2 - m);
        const float inv = 1.0f / (e0 + e1 + e2);
        res[k * 3 + 0] = e0 * inv;
        res[k * 3 + 1] = e1 * inv;
        res[k * 3 + 2] = e2 * inv;
    }

    float4* __restrict__ ov = (float4*)(out + (size_t)row0 * 3);  // 48B-aligned
    ov[0] = make_float4(res[0], res[1], res[2], res[3]);
    ov[1] = make_float4(res[4], res[5], res[6], res[7]);
    ov[2] = make_float4(res[8], res[9], res[10], res[11]);
}

extern "C" void kernel_launch(void* const* d_in, const int* in_sizes, int n_in,
                              void* d_out, int out_size, void* d_ws, size_t ws_size,
                              hipStream_t stream) {
    const float* x        = (const float*)d_in[0];
    const float* w_in     = (const float*)d_in[1];
    const float* w_hidden = (const float*)d_in[2];
    const float* w_out    = (const float*)d_in[3];
    float* out = (float*)d_out;

    const int nrows = in_sizes[0] / 4;             // x is [B,4]
    const int nthreads = (nrows + 3) / 4;          // 4 rows per thread
    const int block = 256;
    const int grid = (nthreads + block - 1) / block;
    Network_31945966748134_kernel<<<grid, block, 0, stream>>>(
        x, w_in, w_hidden, w_out, out, nrows);
}